// Round 1
// baseline (215.744 us; speedup 1.0000x reference)
//
#include <hip/hip_runtime.h>
#include <math.h>

#define ZEPS  0.01f
#define ZMEAN 0.1307f
#define ZSIGMA 0.3081f

constexpr int D = 1024, H = 4096, O = 10;

using short8 = __attribute__((ext_vector_type(8))) short;
using f32x4  = __attribute__((ext_vector_type(4))) float;
typedef unsigned short ushort_t;

__device__ inline unsigned short f2bf(float x) {  // RNE fp32 -> bf16 bits
    unsigned int u = __float_as_uint(x);
    u += 0x7FFFu + ((u >> 16) & 1u);
    return (unsigned short)(u >> 16);
}
__device__ inline float bf2f(unsigned short h) {
    return __uint_as_float(((unsigned int)h) << 16);
}

// async 16B/lane global->LDS (lds dest = wave-uniform base, lane offset = lane*16)
__device__ inline void gl_lds16(const void* g, void* l) {
    __builtin_amdgcn_global_load_lds(
        (const __attribute__((address_space(1))) unsigned int*)g,
        (__attribute__((address_space(3))) unsigned int*)l, 16, 0, 0);
}

__device__ inline float zval(float xv) {
    float up = fminf(xv + ZEPS, 1.f);
    float lo = fmaxf(xv - ZEPS, 0.f);
    return (up + lo - ZMEAN) / ZSIGMA;
}
__device__ inline float zdia(float xv) {
    return fminf(xv + ZEPS, 1.f) / ZSIGMA;
}

// ---------------------------------------------------------------------------
__device__ inline void relu_params(float v, float r, float& vout, float& aout, float& tout) {
    float u = v + r, l = v - r;
    float denom = u - l;
    float slope = u / (denom == 0.f ? 1.f : denom);
    float term = (1.f - slope) * u * 0.5f;
    bool dead = (u <= 0.f);
    bool crossing = (u > 0.f) && (l < 0.f);
    vout = dead ? 0.f : (crossing ? (slope * v + term) : v);
    aout = dead ? 0.f : (crossing ? slope : 1.f);
    tout = (!dead && crossing) ? term : 0.f;
}

// ---------------------------------------------------------------------------
// wave-per-row: v1 = W1@values+b1 ; r1 = |W1| @ d ; ReLU-1 params
__global__ __launch_bounds__(256) void k_layer1(const float* __restrict__ W1, const float* __restrict__ b1,
                                                const float* __restrict__ x,
                                                float* __restrict__ v1p, float* __restrict__ a1,
                                                float* __restrict__ t1) {
    int wid = threadIdx.x >> 6, lane = threadIdx.x & 63;
    int i = blockIdx.x * 4 + wid;
    const float* row = W1 + (size_t)i * D;
    float sv = 0.f, sr = 0.f;
#pragma unroll
    for (int it = 0; it < 4; ++it) {
        int j = it * 256 + lane * 4;
        float4 w = *(const float4*)&row[j];
        float4 xx = *(const float4*)&x[j];
        sv += w.x * zval(xx.x) + w.y * zval(xx.y) + w.z * zval(xx.z) + w.w * zval(xx.w);
        sr += fabsf(w.x) * zdia(xx.x) + fabsf(w.y) * zdia(xx.y) +
              fabsf(w.z) * zdia(xx.z) + fabsf(w.w) * zdia(xx.w);
    }
#pragma unroll
    for (int m = 1; m <= 32; m <<= 1) {
        sv += __shfl_xor(sv, m, 64);
        sr += __shfl_xor(sr, m, 64);
    }
    if (lane == 0) {
        float vo, ao, to;
        relu_params(sv + b1[i], sr, vo, ao, to);
        v1p[i] = vo; a1[i] = ao; t1[i] = to;
    }
}

// W1sT[j][k] = bf16( a1[k] * W1[k][j] * d[j] )  — transposed, k-contiguous
__global__ __launch_bounds__(256) void k_scaleT(const float* __restrict__ W1, const float* __restrict__ a1,
                                                const float* __restrict__ x,
                                                ushort_t* __restrict__ W1sT) {
    __shared__ float tile[32][33];
    int j0 = blockIdx.x * 32, k0 = blockIdx.y * 32;
    int r = threadIdx.x >> 3;
    int c = (threadIdx.x & 7) * 4;
    float4 w = *(const float4*)&W1[(size_t)(k0 + r) * D + j0 + c];
    float4 xx = *(const float4*)&x[j0 + c];
    float a = a1[k0 + r];
    tile[r][c + 0] = a * w.x * zdia(xx.x);
    tile[r][c + 1] = a * w.y * zdia(xx.y);
    tile[r][c + 2] = a * w.z * zdia(xx.z);
    tile[r][c + 3] = a * w.w * zdia(xx.w);
    __syncthreads();
    ushort4 o;
    o.x = f2bf(tile[c + 0][r]);
    o.y = f2bf(tile[c + 1][r]);
    o.z = f2bf(tile[c + 2][r]);
    o.w = f2bf(tile[c + 3][r]);
    *(ushort4*)&W1sT[(size_t)(j0 + r) * H + k0 + c] = o;
}

// ---------------------------------------------------------------------------
// NEW: streaming W2 fp32 -> bf16 pre-conversion, fused with the full fp32
// matvecs v2raw = W2 @ v1p and t2raw = W2 @ t1 (wave-per-row).
__global__ __launch_bounds__(256) void k_w2conv(const float* __restrict__ W2,
                                                const float* __restrict__ v1p,
                                                const float* __restrict__ t1,
                                                ushort_t* __restrict__ W2bf,
                                                float* __restrict__ v2raw,
                                                float* __restrict__ t2raw) {
    int wid = threadIdx.x >> 6, lane = threadIdx.x & 63;
    int i = blockIdx.x * 4 + wid;
    const float* row = W2 + (size_t)i * H;
    ushort_t* orow = W2bf + (size_t)i * H;
    float sv = 0.f, st = 0.f;
#pragma unroll 4
    for (int it = 0; it < 16; ++it) {
        int j = it * 256 + lane * 4;
        float4 w = *(const float4*)&row[j];
        float4 vv = *(const float4*)&v1p[j];
        float4 tt = *(const float4*)&t1[j];
        sv += w.x * vv.x + w.y * vv.y + w.z * vv.z + w.w * vv.w;
        st += w.x * tt.x + w.y * tt.y + w.z * tt.z + w.w * tt.w;
        ushort4 o;
        o.x = f2bf(w.x); o.y = f2bf(w.y); o.z = f2bf(w.z); o.w = f2bf(w.w);
        *(ushort4*)&orow[j] = o;
    }
#pragma unroll
    for (int m = 1; m <= 32; m <<= 1) {
        sv += __shfl_xor(sv, m, 64);
        st += __shfl_xor(st, m, 64);
    }
    if (lane == 0) { v2raw[i] = sv; t2raw[i] = st; }
}

// ---------------------------------------------------------------------------
// eps2(bf16) = bf16(W2) @ W1sT^T, split-K=2. Clean m97-structure bf16 GEMM:
// both operands DMA'd via global_load_lds width=16 with pre-swizzled global
// source, double-buffered LDS, 1 barrier per K-step. xb pinned to XCD so each
// XCD's 1MB B-slice stays L2-resident.
#define GBK 64
__global__ __launch_bounds__(256) void k_gemm_mfma(const ushort_t* __restrict__ A,
                                                   const ushort_t* __restrict__ B,
                                                   ushort_t* __restrict__ C) {
    const int N = D, K = H;
    __shared__ __align__(16) ushort_t As[2][128 * GBK];   // 2 x 16 KB
    __shared__ __align__(16) ushort_t Bs[2][128 * GBK];   // 2 x 16 KB
    int b = blockIdx.x;
    int xb = b & 7;          // N-tile == XCD id (round-robin dispatch heuristic)
    int v = b >> 3;          // 0..63
    int z = v & 1;           // split-K half
    int y = v >> 1;          // 0..31 M-tile
    int tid = threadIdx.x;
    int wave = tid >> 6, lane = tid & 63;
    int bm = y * 128, bn = xb * 128;
    int kbeg = z * (K / 2);
    ushort_t* Cz = C + (size_t)z * ((size_t)H * D);
    int wm = (wave >> 1) * 64, wn = (wave & 1) * 64;

    int srow = lane >> 3, sc = lane & 7, scp = sc ^ srow;   // staging geometry
    int r15 = lane & 15, quad = lane >> 4, key = r15 & 7;   // read-side swizzle

    const int S = (K / 2) / GBK;  // 32

    auto issue = [&](int s, int buf) {
#pragma unroll
        for (int g = 0; g < 4; ++g) {
            int row = wave * 32 + g * 8;
            gl_lds16(&A[(size_t)(bm + row + srow) * K + kbeg + s * GBK + scp * 8],
                     &As[buf][row * GBK]);
            gl_lds16(&B[(size_t)(bn + row + srow) * K + kbeg + s * GBK + scp * 8],
                     &Bs[buf][row * GBK]);
        }
    };

    f32x4 acc[4][4];
#pragma unroll
    for (int p = 0; p < 4; ++p)
#pragma unroll
        for (int q = 0; q < 4; ++q) acc[p][q] = (f32x4){0.f, 0.f, 0.f, 0.f};

    issue(0, 0);
    __syncthreads();   // drains DMA (compiler emits vmcnt(0) before s_barrier)

    for (int s = 0; s < S; ++s) {
        int buf = s & 1, nbuf = buf ^ 1;
        if (s + 1 < S) issue(s + 1, nbuf);   // prefetch overlaps MFMA below
#pragma unroll
        for (int kk = 0; kk < 2; ++kk) {
            short8 af[4], bfr[4];
#pragma unroll
            for (int mt = 0; mt < 4; ++mt)
                af[mt] = *(const short8*)&As[buf][(wm + mt * 16 + r15) * GBK + (((kk * 4 + quad) ^ key)) * 8];
#pragma unroll
            for (int nt = 0; nt < 4; ++nt)
                bfr[nt] = *(const short8*)&Bs[buf][(wn + nt * 16 + r15) * GBK + (((kk * 4 + quad) ^ key)) * 8];
#pragma unroll
            for (int mt = 0; mt < 4; ++mt)
#pragma unroll
                for (int nt = 0; nt < 4; ++nt)
                    acc[mt][nt] = __builtin_amdgcn_mfma_f32_16x16x32_bf16(af[mt], bfr[nt], acc[mt][nt], 0, 0, 0);
        }
        __syncthreads();
    }

    // epilogue: C row = quad*4+reg, col = lane&15; bf16 store
#pragma unroll
    for (int mt = 0; mt < 4; ++mt) {
        int gr = bm + wm + mt * 16 + quad * 4;
#pragma unroll
        for (int nt = 0; nt < 4; ++nt) {
            int gc = bn + wn + nt * 16 + r15;
            Cz[(size_t)(gr + 0) * N + gc] = f2bf(acc[mt][nt][0]);
            Cz[(size_t)(gr + 1) * N + gc] = f2bf(acc[mt][nt][1]);
            Cz[(size_t)(gr + 2) * N + gc] = f2bf(acc[mt][nt][2]);
            Cz[(size_t)(gr + 3) * N + gc] = f2bf(acc[mt][nt][3]);
        }
    }
}

// wave-per-row: r2 = rowsum|e1+e2|+|t2col| ; ReLU-2 params from v2raw/t2raw
// fused w3s[i][o] = W3[o][i]*a2[i]   (e1,e2 are bf16 split-K halves)
__global__ __launch_bounds__(256) void k_relu2(const ushort_t* __restrict__ e1, const ushort_t* __restrict__ e2,
                                               const float* __restrict__ v2raw, const float* __restrict__ t2raw,
                                               const float* __restrict__ b2, const float* __restrict__ W3,
                                               float* __restrict__ v2p, float* __restrict__ a2,
                                               float* __restrict__ t2, float* __restrict__ t2col,
                                               float* __restrict__ w3s) {
    int wid = threadIdx.x >> 6, lane = threadIdx.x & 63;
    int i = blockIdx.x * 4 + wid;
    float s = 0.f;
#pragma unroll
    for (int it = 0; it < 2; ++it) {
        int j = lane * 8 + it * 512;
        ushort4 a0 = *(const ushort4*)&e1[(size_t)i * D + j];
        ushort4 a1v = *(const ushort4*)&e1[(size_t)i * D + j + 4];
        ushort4 b0 = *(const ushort4*)&e2[(size_t)i * D + j];
        ushort4 b1v = *(const ushort4*)&e2[(size_t)i * D + j + 4];
        s += fabsf(bf2f(a0.x) + bf2f(b0.x)) + fabsf(bf2f(a0.y) + bf2f(b0.y))
           + fabsf(bf2f(a0.z) + bf2f(b0.z)) + fabsf(bf2f(a0.w) + bf2f(b0.w))
           + fabsf(bf2f(a1v.x) + bf2f(b1v.x)) + fabsf(bf2f(a1v.y) + bf2f(b1v.y))
           + fabsf(bf2f(a1v.z) + bf2f(b1v.z)) + fabsf(bf2f(a1v.w) + bf2f(b1v.w));
    }
#pragma unroll
    for (int m = 1; m <= 32; m <<= 1) s += __shfl_xor(s, m, 64);
    float ve = v2raw[i];
    float te = t2raw[i];
    float vo, ao, to;
    relu_params(ve + b2[i], s + fabsf(te), vo, ao, to);
    if (lane == 0) { v2p[i] = vo; a2[i] = ao; t2[i] = to; t2col[i] = te; }
    if (lane < O) w3s[(size_t)i * O + lane] = W3[(size_t)lane * H + i] * ao;
}

// pbuf[o][ib][j] = sum over 128-row i-slice ib of w3s[i][o] * (e1+e2)[i][j]  (bf16 e)
__global__ __launch_bounds__(256) void k_eps3a(const ushort_t* __restrict__ e1, const ushort_t* __restrict__ e2,
                                               const float* __restrict__ w3s,
                                               float* __restrict__ pbuf) {
    int jb = blockIdx.x, ib = blockIdx.y;      // 16 x 32
    int jj = threadIdx.x & 15, s = threadIdx.x >> 4;
    int j = jb * 64 + jj * 4;
    int i0 = ib * 128 + s * 8;
    float acc[4][O];
#pragma unroll
    for (int c = 0; c < 4; ++c)
#pragma unroll
        for (int o = 0; o < O; ++o) acc[c][o] = 0.f;
    for (int ii = 0; ii < 8; ++ii) {
        int i = i0 + ii;
        ushort4 a = *(const ushort4*)&e1[(size_t)i * D + j];
        ushort4 b = *(const ushort4*)&e2[(size_t)i * D + j];
        float e0 = bf2f(a.x) + bf2f(b.x), ee1 = bf2f(a.y) + bf2f(b.y);
        float ee2 = bf2f(a.z) + bf2f(b.z), ee3 = bf2f(a.w) + bf2f(b.w);
        const float* w = &w3s[(size_t)i * O];
#pragma unroll
        for (int o = 0; o < O; ++o) {
            float wo = w[o];
            acc[0][o] += wo * e0; acc[1][o] += wo * ee1;
            acc[2][o] += wo * ee2; acc[3][o] += wo * ee3;
        }
    }
    __shared__ float sm[16][64][O];  // 40 KB
#pragma unroll
    for (int c = 0; c < 4; ++c)
#pragma unroll
        for (int o = 0; o < O; ++o) sm[s][jj * 4 + c][o] = acc[c][o];
    __syncthreads();
    for (int idx = threadIdx.x; idx < 64 * O; idx += 256) {
        int col = idx / O, o = idx % O;
        float t = 0.f;
#pragma unroll
        for (int ss = 0; ss < 16; ++ss) t += sm[ss][col][o];
        pbuf[((size_t)o * 32 + ib) * D + jb * 64 + col] = t;
    }
}

// fused eps3b + final
__global__ __launch_bounds__(256) void k_final(const float* __restrict__ W3, const float* __restrict__ b3,
                                               const float* __restrict__ v2p, const float* __restrict__ a2,
                                               const float* __restrict__ t2col, const float* __restrict__ t2,
                                               const float* __restrict__ pbuf, float* __restrict__ out) {
    int o = blockIdx.x, tid = threadIdx.x;
    float s3 = 0.f;
    for (int j = tid; j < D; j += 256) {
        float t = 0.f;
#pragma unroll
        for (int ib = 0; ib < 32; ++ib) t += pbuf[((size_t)o * 32 + ib) * D + j];
        s3 += fabsf(t);
    }
    const float* row = W3 + (size_t)o * H;
    float sv = 0.f, s1 = 0.f, s2 = 0.f;
    for (int i = tid; i < H; i += 256) {
        float w = row[i];
        sv += w * v2p[i];
        s1 += w * a2[i] * t2col[i];
        s2 += w * t2[i];
    }
    __shared__ float ra[256], rb[256], rc[256], rd[256];
    ra[tid] = sv; rb[tid] = s1; rc[tid] = s2; rd[tid] = s3;
    __syncthreads();
    for (int off = 128; off; off >>= 1) {
        if (tid < off) {
            ra[tid] += ra[tid + off]; rb[tid] += rb[tid + off];
            rc[tid] += rc[tid + off]; rd[tid] += rd[tid + off];
        }
        __syncthreads();
    }
    if (tid == 0) {
        float v3 = ra[0] + b3[o];
        float rr = rd[0] + fabsf(rb[0]) + fabsf(rc[0]);
        out[o] = v3 + rr;       // u
        out[O + o] = v3 - rr;   // l
    }
}

// ---------------------------------------------------------------------------
extern "C" void kernel_launch(void* const* d_in, const int* in_sizes, int n_in,
                              void* d_out, int out_size, void* d_ws, size_t ws_size,
                              hipStream_t stream) {
    const float* x  = (const float*)d_in[0];
    const float* W1 = (const float*)d_in[1];
    const float* b1 = (const float*)d_in[2];
    const float* W2 = (const float*)d_in[3];
    const float* b2 = (const float*)d_in[4];
    const float* W3 = (const float*)d_in[5];
    const float* b3 = (const float*)d_in[6];
    float* out = (float*)d_out;

    float* p = (float*)d_ws;
    float* v1p    = p; p += H;
    float* a1     = p; p += H;
    float* t1     = p; p += H;
    float* t2col  = p; p += H;
    float* v2p    = p; p += H;
    float* a2     = p; p += H;
    float* t2     = p; p += H;
    float* v2raw  = p; p += H;
    float* t2raw  = p; p += H;
    float* w3s    = p; p += H * O + 8;
    float* pbuf   = p; p += 32 * O * D;                       // 1.25 MB
    ushort_t* eps2  = (ushort_t*)p;                           // 2 x 8 MB bf16 (split-K partials)
    ushort_t* W1sT  = eps2 + (size_t)2 * H * D;               // 8 MB bf16
    ushort_t* W2bf  = W1sT + (size_t)H * D;                   // 32 MB bf16
    ushort_t* eps2b = eps2 + (size_t)H * D;

    k_layer1<<<H / 4, 256, 0, stream>>>(W1, b1, x, v1p, a1, t1);
    k_scaleT<<<dim3(D / 32, H / 32), 256, 0, stream>>>(W1, a1, x, W1sT);
    k_w2conv<<<H / 4, 256, 0, stream>>>(W2, v1p, t1, W2bf, v2raw, t2raw);
    k_gemm_mfma<<<512, 256, 0, stream>>>(W2bf, W1sT, eps2);
    k_relu2<<<H / 4, 256, 0, stream>>>(eps2, eps2b, v2raw, t2raw, b2, W3, v2p, a2, t2, t2col, w3s);
    k_eps3a<<<dim3(D / 64, 32), 256, 0, stream>>>(eps2, eps2b, w3s, pbuf);
    k_final<<<O, 256, 0, stream>>>(W3, b3, v2p, a2, t2col, t2, pbuf, out);
}